// Round 3
// baseline (1211.413 us; speedup 1.0000x reference)
//
#include <hip/hip_runtime.h>
#include <hip/hip_bf16.h>
#include <float.h>
#include <limits.h>

// ---- problem constants ----
#define NROWS 3136        // 64 items * 49 positions
#define NROWS_PAD 3200    // padded to 25 * 128 for GEMM tiles
#define NKEYS 65536
#define KDIM 512
#define NITEMS 64
#define HW 49
#define TOPK 16
#define CAND 32           // approx candidates kept per row (margin for exact rescore)
#define LANE_L 12         // per-lane list depth in streaming top-k
#define TKW 4             // waves per topk block
#define ALPHA_C 0.1f

typedef unsigned short u16;
typedef unsigned int u32;
typedef __attribute__((ext_vector_type(8))) short bfrag;   // 8 bf16 = 4 VGPR (MFMA A/B frag)
typedef __attribute__((ext_vector_type(4))) float f32x4;   // MFMA C/D frag

// round-to-nearest-even f32 -> bf16 bits (inputs finite)
__device__ inline u16 f2bf(float x) {
  u32 u = __float_as_uint(x);
  u32 r = u + 0x7fffu + ((u >> 16) & 1u);
  return (u16)(r >> 16);
}

// ---------------- prep: normalize queries ----------------
// queries layout (64, 512, 7, 7): q[b,p,c] = queries[b*512*49 + c*49 + p]
__global__ __launch_bounds__(256) void prep_qnorm(const float* __restrict__ q,
        float* __restrict__ q_norm, u16* __restrict__ qbf) {
  int row = blockIdx.x;
  int t = threadIdx.x;
  if (row >= NROWS) {            // pad rows: zero bf16 so GEMM is defined
    qbf[(size_t)row * KDIM + t] = 0;
    qbf[(size_t)row * KDIM + t + 256] = 0;
    return;
  }
  int b = row / HW, p = row % HW;
  const float* base = q + (size_t)b * KDIM * HW + p;
  float v0 = base[(size_t)t * HW];
  float v1 = base[(size_t)(t + 256) * HW];
  __shared__ float red[256];
  red[t] = v0 * v0 + v1 * v1;
  __syncthreads();
  for (int st = 128; st > 0; st >>= 1) {
    if (t < st) red[t] += red[t + st];
    __syncthreads();
  }
  float nrm = fmaxf(sqrtf(red[0]), 1e-12f);   // clip(norm, 1e-12)
  float w0 = v0 / nrm, w1 = v1 / nrm;
  q_norm[(size_t)row * KDIM + t] = w0;
  q_norm[(size_t)row * KDIM + t + 256] = w1;
  qbf[(size_t)row * KDIM + t] = f2bf(w0);
  qbf[(size_t)row * KDIM + t + 256] = f2bf(w1);
}

// ---------------- prep: keys -> bf16 ----------------
__global__ __launch_bounds__(256) void prep_keys(const float* __restrict__ mk, u16* __restrict__ kbf) {
  size_t i = ((size_t)blockIdx.x * 256 + threadIdx.x) * 8;
  float4 a = *(const float4*)(mk + i);
  float4 b = *(const float4*)(mk + i + 4);
  bfrag v;
  v[0] = (short)f2bf(a.x); v[1] = (short)f2bf(a.y);
  v[2] = (short)f2bf(a.z); v[3] = (short)f2bf(a.w);
  v[4] = (short)f2bf(b.x); v[5] = (short)f2bf(b.y);
  v[6] = (short)f2bf(b.z); v[7] = (short)f2bf(b.w);
  *(bfrag*)(kbf + i) = v;
}

// ---------------- misc init / class scan ----------------
__global__ void init_first(int* first_idx) {
  int t = threadIdx.x;
  if (t < 100) first_idx[t] = INT_MAX;
}
__global__ __launch_bounds__(256) void init_run(float* run_sim, int* run_idx) {
  int i = blockIdx.x * 256 + threadIdx.x;   // NROWS*CAND entries exactly
  run_sim[i] = -FLT_MAX;
  run_idx[i] = INT_MAX;
}
__global__ __launch_bounds__(256) void scan_vals(const int* __restrict__ mvals, int* first_idx) {
  int i = blockIdx.x * 256 + threadIdx.x;
  atomicMin(&first_idx[mvals[i]], i);       // first occurrence == argmax(hit)
}
__global__ void item_info(const int* __restrict__ targets, const int* __restrict__ first_idx,
                          int* item_saf, int* item_ex) {
  int b = threadIdx.x;   // 64
  int fi = first_idx[targets[b]];
  int ex = (fi != INT_MAX);
  item_ex[b] = ex;
  item_saf[b] = ex ? fi : 0;   // argmax(all-False) == 0 in reference
}

// ---------------- bf16 MFMA GEMM: sims chunk = qbf @ kbf^T (bf16 out) ----------------
// m97-style 128x128 tile, BK=32, 4 waves (each 64x64 via 4x4 16x16x32 frags),
// global_load_lds width 16, linear LDS. Grid: x = row-panel (25, fastest) so
// consecutive blocks reuse one B-tile from L2; y = key-tile.
// Epilogue: acc -> LDS [128][144] u16 -> coalesced uint4 row-major stores.
__device__ inline void gload16(const void* g, void* l) {
  __builtin_amdgcn_global_load_lds((const __attribute__((address_space(1))) unsigned int*)g,
                                   (__attribute__((address_space(3))) unsigned int*)l, 16, 0, 0);
}

#define CT_LD 144   // u16 elements per Ct row (288B; keeps 16B alignment per row)

__global__ __launch_bounds__(256) void gemm_chunk(const u16* __restrict__ A, const u16* __restrict__ B,
        u16* __restrict__ C, int ldc) {
  __shared__ __align__(16) char lds[128 * CT_LD * 2];   // 36864 B; aliases As/Bs then Ct
  u16* As = (u16*)lds;                                  // [128][32]
  u16* Bs = (u16*)(lds + 8192);                         // [128][32]
  u16* Ct = (u16*)lds;                                  // [128][CT_LD]
  int tid = threadIdx.x;
  int lane = tid & 63, wv = tid >> 6;
  int wr = wv >> 1, wc = wv & 1;
  int mbase = blockIdx.x * 128;   // row panel (fastest-varying)
  int nbase = blockIdx.y * 128;   // key tile
  const u16* Ag = A + (size_t)mbase * KDIM;
  const u16* Bg = B + (size_t)nbase * KDIM;

  f32x4 acc[4][4];
  #pragma unroll
  for (int i = 0; i < 4; ++i)
    #pragma unroll
    for (int j = 0; j < 4; ++j)
      acc[i][j] = (f32x4){0.f, 0.f, 0.f, 0.f};

  int lrow = lane & 15;
  int k8 = (lane >> 4) * 8;     // contiguous 8-bf16 K-slice per lane

  for (int kk = 0; kk < KDIM; kk += 32) {
    #pragma unroll
    for (int s = 0; s < 2; ++s) {
      int ch = s * 256 + wv * 64 + lane;      // 512 x 16B chunks per 8KB tile
      int r = ch >> 2, c = (ch & 3) * 8;
      gload16(Ag + (size_t)r * KDIM + kk + c, lds + (size_t)(s * 256 + wv * 64) * 16);
      gload16(Bg + (size_t)r * KDIM + kk + c, lds + 8192 + (size_t)(s * 256 + wv * 64) * 16);
    }
    __syncthreads();
    bfrag a[4], b[4];
    #pragma unroll
    for (int i = 0; i < 4; ++i) {
      a[i] = *(const bfrag*)&As[(wr * 64 + i * 16 + lrow) * 32 + k8];
      b[i] = *(const bfrag*)&Bs[(wc * 64 + i * 16 + lrow) * 32 + k8];
    }
    #pragma unroll
    for (int i = 0; i < 4; ++i)
      #pragma unroll
      for (int j = 0; j < 4; ++j)
        acc[i][j] = __builtin_amdgcn_mfma_f32_16x16x32_bf16(a[i], b[j], acc[i][j], 0, 0, 0);
    __syncthreads();   // also protects the Ct alias below on the last iteration
  }
  // C/D layout: col = lane&15, row = (lane>>4)*4 + reg  [m89-verified]
  int r0l = wr * 64 + (lane >> 4) * 4;
  int c0l = wc * 64 + lrow;
  #pragma unroll
  for (int i = 0; i < 4; ++i)
    #pragma unroll
    for (int j = 0; j < 4; ++j)
      #pragma unroll
      for (int r = 0; r < 4; ++r)
        Ct[(r0l + i * 16 + r) * CT_LD + c0l + j * 16] = f2bf(acc[i][j][r]);
  __syncthreads();
  // coalesced writeout: 2048 chunks of 8 u16 (16B), 8 per thread
  #pragma unroll
  for (int it = 0; it < 8; ++it) {
    int chnk = it * 256 + tid;
    int rr = chnk >> 4, cg = chnk & 15;
    uint4 v = *(const uint4*)&Ct[rr * CT_LD + cg * 8];
    *(uint4*)(C + (size_t)(mbase + rr) * ldc + nbase + cg * 8) = v;
  }
}

// ---------------- streaming approx top-32 per row ----------------
// 1 block (4 waves) per row; wave w scans quarter-segment w. Per-lane sorted
// top-12 (static-indexed; rule #20), per-wave top-CAND extraction via wave
// argmax, then lane-0 5-way merge (4 wave lists + running list).
__device__ inline void ins_top(float (&s)[LANE_L], int (&ix)[LANE_L], float vv, int cidx) {
  if (vv > s[LANE_L - 1]) {
    #pragma unroll
    for (int k = LANE_L - 1; k >= 0; --k) {   // descending: reads old s[k-1]
      bool g  = vv > s[k];
      bool gp = (k > 0) && (vv > s[k - 1]);
      float ns = g ? (gp ? s[k - 1] : vv) : s[k];
      int   ni = g ? (gp ? ix[k - 1] : cidx) : ix[k];
      s[k] = ns; ix[k] = ni;
    }
  }
}

__global__ __launch_bounds__(256) void topk_update(const u16* __restrict__ C, int nk, int key_base,
        float* __restrict__ run_sim, int* __restrict__ run_idx) {
  int row = blockIdx.x;
  int tid = threadIdx.x, lane = tid & 63, wv = tid >> 6;
  int seg = nk >> 2;                           // nk multiple of 2048 -> seg multiple of 512
  const u16* crow = C + (size_t)row * nk + (size_t)wv * seg;
  int ibase = key_base + wv * seg;

  float s[LANE_L]; int ix[LANE_L];
  #pragma unroll
  for (int k = 0; k < LANE_L; ++k) { s[k] = -FLT_MAX; ix[k] = INT_MAX; }

  int iters = seg >> 9;                        // 512 keys per wave-iter (8 bf16/lane)
  for (int t = 0; t < iters; ++t) {
    uint4 v = *(const uint4*)(crow + (size_t)t * 512 + lane * 8);
    int ib = ibase + t * 512 + lane * 8;
    // bf16 bits -> f32 exactly: low half <<16, high half masked
    ins_top(s, ix, __uint_as_float(v.x << 16), ib + 0);
    ins_top(s, ix, __uint_as_float(v.x & 0xffff0000u), ib + 1);
    ins_top(s, ix, __uint_as_float(v.y << 16), ib + 2);
    ins_top(s, ix, __uint_as_float(v.y & 0xffff0000u), ib + 3);
    ins_top(s, ix, __uint_as_float(v.z << 16), ib + 4);
    ins_top(s, ix, __uint_as_float(v.z & 0xffff0000u), ib + 5);
    ins_top(s, ix, __uint_as_float(v.w << 16), ib + 6);
    ins_top(s, ix, __uint_as_float(v.w & 0xffff0000u), ib + 7);
  }

  __shared__ float msim[TKW][CAND + 1]; __shared__ int midx[TKW][CAND + 1];
  __shared__ float rs[CAND + 1];        __shared__ int ri[CAND + 1];
  for (int r = 0; r < CAND; ++r) {               // per-wave extraction (independent)
    float c = s[0]; int ci = ix[0];
    for (int off = 32; off > 0; off >>= 1) {
      float oc = __shfl_xor(c, off);
      int   oi = __shfl_xor(ci, off);
      if (oc > c || (oc == c && oi < ci)) { c = oc; ci = oi; }
    }
    if (lane == 0) { msim[wv][r] = c; midx[wv][r] = ci; }
    if (ci == ix[0]) {                           // unique owner pops (idx unique)
      #pragma unroll
      for (int k = 0; k < LANE_L - 1; ++k) { s[k] = s[k + 1]; ix[k] = ix[k + 1]; }
      s[LANE_L - 1] = -FLT_MAX; ix[LANE_L - 1] = INT_MAX;
    }
  }
  if (lane == 0) { msim[wv][CAND] = -FLT_MAX; midx[wv][CAND] = INT_MAX; }
  if (tid < CAND) { rs[tid] = run_sim[row * CAND + tid]; ri[tid] = run_idx[row * CAND + tid]; }
  if (tid == 0)  { rs[CAND] = -FLT_MAX; ri[CAND] = INT_MAX; }
  __syncthreads();
  if (tid == 0) {   // 5-way merge of sorted-desc lists -> running top-32
    int p0 = 0, p1 = 0, p2 = 0, p3 = 0, pr = 0;
    for (int o = 0; o < CAND; ++o) {
      float bs = rs[pr]; int bi = ri[pr]; int src = 4;
      float h; int hi;
      h = msim[0][p0]; hi = midx[0][p0]; if (h > bs || (h == bs && hi < bi)) { bs = h; bi = hi; src = 0; }
      h = msim[1][p1]; hi = midx[1][p1]; if (h > bs || (h == bs && hi < bi)) { bs = h; bi = hi; src = 1; }
      h = msim[2][p2]; hi = midx[2][p2]; if (h > bs || (h == bs && hi < bi)) { bs = h; bi = hi; src = 2; }
      h = msim[3][p3]; hi = midx[3][p3]; if (h > bs || (h == bs && hi < bi)) { bs = h; bi = hi; src = 3; }
      run_sim[row * CAND + o] = bs; run_idx[row * CAND + o] = bi;
      if (src == 0) ++p0; else if (src == 1) ++p1; else if (src == 2) ++p2;
      else if (src == 3) ++p3; else ++pr;
    }
  }
}

// ---------------- exact fp32 rescore of 32 candidates + safety dot ----------------
__global__ __launch_bounds__(64) void rescore(const float* __restrict__ q_norm, const float* __restrict__ mkeys,
        const int* __restrict__ mvals, const int* __restrict__ run_idx, const int* __restrict__ item_saf,
        float* __restrict__ t16_sim, int* __restrict__ t16_val, int* __restrict__ nearest_val,
        float* __restrict__ safety_sim) {
  int row = blockIdx.x, lane = threadIdx.x;
  int b = row / HW;
  const float* qr = q_norm + (size_t)row * KDIM;
  float4 q0 = *(const float4*)(qr + lane * 8);
  float4 q1 = *(const float4*)(qr + lane * 8 + 4);
  __shared__ float es[CAND]; __shared__ int ei[CAND];

  for (int c = 0; c < CAND; ++c) {
    int ki = run_idx[row * CAND + c];
    float p = -FLT_MAX;
    if (ki >= 0 && ki < NKEYS) {
      const float* kr = mkeys + (size_t)ki * KDIM;
      float4 k0 = *(const float4*)(kr + lane * 8);
      float4 k1 = *(const float4*)(kr + lane * 8 + 4);
      p = q0.x * k0.x + q0.y * k0.y + q0.z * k0.z + q0.w * k0.w
        + q1.x * k1.x + q1.y * k1.y + q1.z * k1.z + q1.w * k1.w;
      for (int off = 32; off > 0; off >>= 1) p += __shfl_xor(p, off);
    }
    if (lane == 0) { es[c] = p; ei[c] = (ki >= 0 && ki < NKEYS) ? ki : -1; }
  }
  {
    int ks = item_saf[b];
    const float* kr = mkeys + (size_t)ks * KDIM;
    float4 k0 = *(const float4*)(kr + lane * 8);
    float4 k1 = *(const float4*)(kr + lane * 8 + 4);
    float p = q0.x * k0.x + q0.y * k0.y + q0.z * k0.z + q0.w * k0.w
            + q1.x * k1.x + q1.y * k1.y + q1.z * k1.z + q1.w * k1.w;
    for (int off = 32; off > 0; off >>= 1) p += __shfl_xor(p, off);
    if (lane == 0) safety_sim[row] = p;
  }
  __syncthreads();
  if (lane == 0) {   // exact top-16, tie -> lower key index (jax.lax.top_k)
    for (int r = 0; r < TOPK; ++r) {
      float bs = -FLT_MAX; int bi = INT_MAX, bc = -1;
      for (int c = 0; c < CAND; ++c) {
        if (ei[c] < 0) continue;
        if (es[c] > bs || (es[c] == bs && ei[c] < bi)) { bs = es[c]; bi = ei[c]; bc = c; }
      }
      if (bc < 0) { bs = 0.f; bi = 0; } else ei[bc] = -1;
      t16_sim[row * TOPK + r] = bs;
      t16_val[row * TOPK + r] = mvals[bi];
      if (r == 0) nearest_val[row] = mvals[bi];
    }
  }
}

// ---------------- per-item mode vote + margin loss ----------------
__global__ __launch_bounds__(64) void item_loss(const float* __restrict__ t16_sim, const int* __restrict__ t16_val,
        const int* __restrict__ nearest_val, const float* __restrict__ safety_sim,
        const int* __restrict__ targets, const int* __restrict__ item_ex,
        float* __restrict__ losses, float* __restrict__ out) {
  int b = blockIdx.x, lane = threadIdx.x;
  __shared__ int counts[101];
  counts[lane] = 0;
  if (lane + 64 < 101) counts[lane + 64] = 0;
  __syncthreads();
  float lw = 0.f, lns = 0.f;
  if (lane < HW) {
    int row = b * HW + lane;
    int tgt = targets[b];
    float pos = -FLT_MAX, neg = -FLT_MAX, ns = -FLT_MAX;
    for (int k = 0; k < TOPK; ++k) {
      float sv = t16_sim[row * TOPK + k];
      int vv = t16_val[row * TOPK + k];
      bool m = (vv == tgt);
      pos = fmaxf(pos, m ? sv : 0.0f);   // sims * cmask semantics (zeros included)
      neg = fmaxf(neg, m ? 0.0f : sv);
      ns  = fmaxf(ns,  m ? 0.0f : sv);
    }
    pos = fmaxf(pos, safety_sim[row]);   // safety column: val == tgt -> match
    neg = fmaxf(neg, 0.0f);              // safety contributes 0 to neg
    lw  = fmaxf(neg - pos + ALPHA_C, 0.0f);
    lns = fmaxf(ns + ALPHA_C, 0.0f);
    atomicAdd(&counts[nearest_val[row] + 1], 1);
  }
  __syncthreads();
  for (int off = 32; off > 0; off >>= 1) {
    lw  += __shfl_xor(lw, off);
    lns += __shfl_xor(lns, off);
  }
  if (lane == 0) {
    int bi = 0, bc = counts[0];
    for (int c = 1; c < 101; ++c)
      if (counts[c] > bc) { bc = counts[c]; bi = c; }   // first max (argmax)
    out[b] = (float)(bi - 1);
    losses[b] = (item_ex[b] ? lw : lns) / 49.0f;        // mean over hw
  }
}

__global__ __launch_bounds__(64) void final_sum(const float* __restrict__ losses, float* __restrict__ out) {
  int lane = threadIdx.x;
  float v = losses[lane];
  for (int off = 32; off > 0; off >>= 1) v += __shfl_xor(v, off);
  if (lane == 0) out[NITEMS] = v;
}

// ---------------- launch ----------------
extern "C" void kernel_launch(void* const* d_in, const int* in_sizes, int n_in,
                              void* d_out, int out_size, void* d_ws, size_t ws_size,
                              hipStream_t stream) {
  const float* queries = (const float*)d_in[0];
  const int*   targets = (const int*)d_in[1];
  const float* m_keys  = (const float*)d_in[2];
  const int*   m_vals  = (const int*)d_in[3];
  float* out = (float*)d_out;
  char* ws = (char*)d_ws;

  size_t off = 0;
  auto alloc = [&](size_t bytes) -> char* {
    char* p = ws + off;
    off += (bytes + 255) & ~(size_t)255;
    return p;
  };
  float* q_norm   = (float*)alloc((size_t)NROWS * KDIM * 4);
  u16*   qbf      = (u16*)  alloc((size_t)NROWS_PAD * KDIM * 2);
  u16*   kbf      = (u16*)  alloc((size_t)NKEYS * KDIM * 2);
  int*   first_ix = (int*)  alloc(128 * 4);
  int*   item_saf = (int*)  alloc(64 * 4);
  int*   item_ex  = (int*)  alloc(64 * 4);
  float* run_sim  = (float*)alloc((size_t)NROWS * CAND * 4);
  int*   run_idx  = (int*)  alloc((size_t)NROWS * CAND * 4);
  float* t16s     = (float*)alloc((size_t)NROWS * TOPK * 4);
  int*   t16v     = (int*)  alloc((size_t)NROWS * TOPK * 4);
  int*   nearv    = (int*)  alloc((size_t)NROWS * 4);
  float* safs     = (float*)alloc((size_t)NROWS * 4);
  float* losses   = (float*)alloc(64 * 4);
  u16*   sims     = (u16*)(ws + off);

  // size the sims chunk from remaining workspace (multiple of 2048 keys so
  // each topk wave's quarter-segment stays a multiple of 512)
  size_t avail = ws_size > off ? ws_size - off : 0;
  long long maxkeys = (long long)(avail / ((size_t)NROWS_PAD * 2));
  int chunk = (int)((maxkeys / 2048) * 2048);
  if (chunk > NKEYS) chunk = NKEYS;
  if (chunk < 2048) chunk = 2048;

  hipLaunchKernelGGL(prep_qnorm, dim3(NROWS_PAD), dim3(256), 0, stream, queries, q_norm, qbf);
  hipLaunchKernelGGL(prep_keys, dim3((NKEYS * KDIM) / 2048), dim3(256), 0, stream, m_keys, kbf);
  hipLaunchKernelGGL(init_first, dim3(1), dim3(128), 0, stream, first_ix);
  hipLaunchKernelGGL(init_run, dim3((NROWS * CAND) / 256), dim3(256), 0, stream, run_sim, run_idx);
  hipLaunchKernelGGL(scan_vals, dim3(NKEYS / 256), dim3(256), 0, stream, m_vals, first_ix);
  hipLaunchKernelGGL(item_info, dim3(1), dim3(64), 0, stream, targets, first_ix, item_saf, item_ex);

  for (int base = 0; base < NKEYS; base += chunk) {
    int nk = (NKEYS - base < chunk) ? (NKEYS - base) : chunk;
    hipLaunchKernelGGL(gemm_chunk, dim3(NROWS_PAD / 128, nk / 128), dim3(256), 0, stream,
                       qbf, kbf + (size_t)base * KDIM, sims, nk);
    hipLaunchKernelGGL(topk_update, dim3(NROWS), dim3(256), 0, stream, sims, nk, base, run_sim, run_idx);
  }

  hipLaunchKernelGGL(rescore, dim3(NROWS), dim3(64), 0, stream,
                     q_norm, m_keys, m_vals, run_idx, item_saf, t16s, t16v, nearv, safs);
  hipLaunchKernelGGL(item_loss, dim3(64), dim3(64), 0, stream,
                     t16s, t16v, nearv, safs, targets, item_ex, losses, out);
  hipLaunchKernelGGL(final_sum, dim3(1), dim3(64), 0, stream, losses, out);
}